// Round 8
// baseline (98.959 us; speedup 1.0000x reference)
//
#include <hip/hip_runtime.h>

// B=4, Sx=Sy=512, H=128, D=2H=256, fp32.
// e1 = exp2(2log2e * x@W1^T)  (stored PRE-SWIZZLED: [b][c][hq][s^hq] float4)
// e2 = exp2(2log2e * y@W2^T)  (linear)
// tanh(s1+s2) = 1 - 2/(e1*e2+1); score = sum_h vc[h]*tanh(.)
// constant sum_h vc[h] dropped (softmax shift-invariant); -2 folded into the
// chunk reduce. P = softmax_s(score); out = P @ x.
// Quad-rcp: v1/f1+..+v4/f4 = (n12*f34+n34*f12)/(f12*f34), one rcp per 4 h.
//
// R8:  harness 256 MiB d_ws fill = ~41 us fixed tax (at HBM roofline).
//      Harness reset memsets ~21-22 us fixed (back-computed from R1).
// R11: FAILED: LDS float atomicAdd under 16-way collision.
// R12: e1 direct from global (no intra-block reuse in G=16 layout).
// R13: proj W-load coalescing (wtrans). 99.3us.
// R14: prefetch/occupancy: -1.3us. LESSON: 8 vs 4 waves/SIMD not binding.
// R15: score+pax fused (P stays in LDS): -2.1us (95.9).
// R16: FAILED (container hang x2): cooperative grid.sync not preserved
//      through hipGraph capture/replay. Never retry.
// R17: wtrans deleted via interleaved-k proj footprint (coalesced W loads
//      in original layout); 2 dispatches. 92.0us.
// R18: final polish: (a) #pragma unroll chunk loop (guarantees v[c] static
//      indexing, rule #20); (b) pax x-prefetch issued BEFORE the softmax
//      barrier (hides cold-L2 latency under softmax). Stop rule: if
//      neutral, controllable budget is exhausted -> roofline.

#define NB 4
#define SEQ 512
#define HDIM 128
#define DDIM 256

static constexpr float TWO_LOG2E = 2.8853900817779268f; // 2*log2(e)
static constexpr float LOG2E     = 1.4426950408889634f;

// ---------------- Kernel A: fused projection + exp2 -----------------------
// 512 blocks x 256 thr. Block = 8 rows of x (gr0<2048) or y, full K=256.
// Thread (hq = tid>>3, ks = tid&7); k-footprint interleaved: float4 index
// kf = u*8 + ks. W loads coalesce in the ORIGINAL [h][k] layout.
__global__ __launch_bounds__(256) void proj_kernel(
    const float* __restrict__ x, const float* __restrict__ y,
    const float* __restrict__ W1, const float* __restrict__ W2,
    float* __restrict__ e1sw, float* __restrict__ e2)
{
    __shared__ float As[2048];      // [8 r][256 k]
    __shared__ float sPr[8192];     // [8 ks][8 r][128 h]
    const int tid = threadIdx.x;
    const int gr0 = blockIdx.x * 8;       // global virtual row base [0,4096)

    const float* in; const float* W; int srow;
    if (gr0 < 2048) { in = x; W = W1; srow = gr0; }
    else            { in = y; W = W2; srow = gr0 - 2048; }

    #pragma unroll
    for (int j = 0; j < 2; ++j) {
        const int idx = tid + j * 256;        // float4 slot [0,512)
        const int r = idx >> 6, kk = idx & 63;
        *(float4*)&As[idx * 4] =
            *(const float4*)&in[(srow + r) * 256 + kk * 4];
    }
    __syncthreads();

    const int hq = tid >> 3;   // h-quad [0,32)
    const int ks = tid & 7;    // k-interleave slot [0,8)
    const float4* W4  = (const float4*)W;    // row stride 64 float4
    const float4* As4 = (const float4*)As;   // row stride 64 float4

    float4 acc4[8];
    #pragma unroll
    for (int r = 0; r < 8; ++r) acc4[r] = make_float4(0.f, 0.f, 0.f, 0.f);

    #pragma unroll
    for (int u = 0; u < 8; ++u) {
        const int kf = u * 8 + ks;           // interleaved k-float4 index
        const float4 w0 = W4[(4 * hq + 0) * 64 + kf];
        const float4 w1 = W4[(4 * hq + 1) * 64 + kf];
        const float4 w2 = W4[(4 * hq + 2) * 64 + kf];
        const float4 w3 = W4[(4 * hq + 3) * 64 + kf];
        #pragma unroll
        for (int r = 0; r < 8; ++r) {
            const float4 a = As4[r * 64 + kf];
            acc4[r].x = fmaf(a.w,w0.w, fmaf(a.z,w0.z, fmaf(a.y,w0.y, fmaf(a.x,w0.x, acc4[r].x))));
            acc4[r].y = fmaf(a.w,w1.w, fmaf(a.z,w1.z, fmaf(a.y,w1.y, fmaf(a.x,w1.x, acc4[r].y))));
            acc4[r].z = fmaf(a.w,w2.w, fmaf(a.z,w2.z, fmaf(a.y,w2.y, fmaf(a.x,w2.x, acc4[r].z))));
            acc4[r].w = fmaf(a.w,w3.w, fmaf(a.z,w3.z, fmaf(a.y,w3.y, fmaf(a.x,w3.x, acc4[r].w))));
        }
    }
    #pragma unroll
    for (int r = 0; r < 8; ++r)
        *(float4*)&sPr[ks * 1024 + r * 128 + hq * 4] = acc4[r];
    __syncthreads();
    {
        const int r = tid >> 5, h4 = tid & 31;
        float4 s = make_float4(0.f, 0.f, 0.f, 0.f);
        #pragma unroll
        for (int k2 = 0; k2 < 8; ++k2) {
            const float4 p = *(const float4*)&sPr[k2 * 1024 + r * 128 + h4 * 4];
            s.x += p.x; s.y += p.y; s.z += p.z; s.w += p.w;
        }
        float4 o;
        o.x = __builtin_amdgcn_exp2f(s.x * TWO_LOG2E);
        o.y = __builtin_amdgcn_exp2f(s.y * TWO_LOG2E);
        o.z = __builtin_amdgcn_exp2f(s.z * TWO_LOG2E);
        o.w = __builtin_amdgcn_exp2f(s.w * TWO_LOG2E);
        const int gr = gr0 + r;
        if (gr < 2048) {
            const int b = gr >> 9, ss = gr & 511;
            const int c = ss >> 6, sl = ss & 63;
            ((float4*)e1sw)[((b * 8 + c) * 32 + h4) * 64 + (sl ^ h4)] = o;
        } else {
            ((float4*)e2)[(gr - 2048) * 32 + h4] = o;
        }
    }
}

// ---------------- Kernel B: fused scores + softmax + P@x -------------------
// 256 blocks x 1024 thr (16 waves). Block = (b, 8 t-rows). Phase 1: wave w
// = h-group hg computes partial scores for ALL 8 t per e1 value (e1 direct
// from global, depth-1 prefetch). Per chunk: partials -> sPartC[c&1],
// barrier, tid<512 accumulate the 16-wave sum into registers v[c] (chunk
// loop FULLY UNROLLED -> v[] static-indexed). Then softmax on v[],
// normalized P into LDS sP[s][t]. Phase 2: pax (first x loads prefetched
// before the softmax barrier); P never touches global. LDS: 64 KB arena.
__global__ __launch_bounds__(1024) void score_pax_kernel(
    const float* __restrict__ e1sw, const float* __restrict__ e2g,
    const float* __restrict__ vc,  const float* __restrict__ x,
    float* __restrict__ out)
{
    __shared__ float sBig[16384];   // 64 KB arena

    const int tid  = threadIdx.x;
    const int b    = blockIdx.x >> 6;
    const int t0   = (blockIdx.x & 63) * 8;
    const int w    = tid >> 6;
    const int lane = tid & 63;
    const int wu   = __builtin_amdgcn_readfirstlane(w);
    const int hg   = wu;               // h-group: quads 2hg, 2hg+1

    // scalar operands: 2 vc quads + 8t x 2 e2 quads (wave-uniform addrs)
    float4 vcs[2];
    float4 e2s[8][2];
    #pragma unroll
    for (int j = 0; j < 2; ++j)
        vcs[j] = *(const float4*)&vc[(hg * 2 + j) * 4];
    #pragma unroll
    for (int t = 0; t < 8; ++t)
        #pragma unroll
        for (int j = 0; j < 2; ++j)
            e2s[t][j] = *(const float4*)&e2g[(b * SEQ + t0 + t) * HDIM + (hg * 2 + j) * 4];

    const float4* e1c = (const float4*)e1sw + b * 16384;  // 8 chunks x 2048

    // fixed per-lane offsets of the two h-quad loads within a chunk
    const int off0 = (hg * 2 + 0) * 64 + (lane ^ (hg * 2 + 0));
    const int off1 = (hg * 2 + 1) * 64 + (lane ^ (hg * 2 + 1));

    float4 e1v0 = e1c[off0];
    float4 e1v1 = e1c[off1];

    float v[8];   // v[c] = score(t = tid>>6, s = c*64 + lane) for tid<512

    #pragma unroll
    for (int c = 0; c < 8; ++c) {
        float4 e1n0 = e1v0, e1n1 = e1v1;
        if (c < 7) {
            const float4* nx = e1c + (c + 1) * 2048;
            e1n0 = nx[off0];
            e1n1 = nx[off1];
        }
        float acc[8];
        #pragma unroll
        for (int t = 0; t < 8; ++t) acc[t] = 0.f;
        #pragma unroll
        for (int j = 0; j < 2; ++j) {
            const float4 e1 = j ? e1v1 : e1v0;
            const float4 vv = vcs[j];
            #pragma unroll
            for (int t = 0; t < 8; ++t) {
                const float4 e2 = e2s[t][j];
                const float f1 = fmaf(e1.x, e2.x, 1.f);
                const float f2 = fmaf(e1.y, e2.y, 1.f);
                const float f3 = fmaf(e1.z, e2.z, 1.f);
                const float f4 = fmaf(e1.w, e2.w, 1.f);
                const float f12 = f1 * f2, f34 = f3 * f4;
                const float n12 = fmaf(vv.x, f2, vv.y * f1);
                const float n34 = fmaf(vv.z, f4, vv.w * f3);
                const float num = fmaf(n12, f34, n34 * f12);
                acc[t] = fmaf(num, __builtin_amdgcn_rcpf(f12 * f34), acc[t]);
            }
        }
        // partials: sPartC[c&1][w][t][64 s]
        float* pb = sBig + (c & 1) * 8192 + wu * 512 + lane;
        #pragma unroll
        for (int t = 0; t < 8; ++t) pb[t * 64] = acc[t];
        __syncthreads();
        if (tid < 512) {
            const int t = tid >> 6, s = tid & 63;
            const float* pc = sBig + (c & 1) * 8192 + t * 64 + s;
            float r = 0.f;
            #pragma unroll
            for (int ww = 0; ww < 16; ++ww) r += pc[ww * 512];
            v[c] = -2.f * r;
        }
        e1v0 = e1n0;
        e1v1 = e1n1;
    }

    // pax x-prefetch: first 4 iterations' x values, issued BEFORE the
    // softmax barrier so their L2 latency hides under softmax + barrier.
    const float4* x4 = (const float4*)x;
    float4 xpre[4];
    #pragma unroll
    for (int si = 0; si < 4; ++si)
        xpre[si] = x4[(b * SEQ + w * 32 + si) * 64 + lane];

    // softmax by tid<512 (thread (t,s) holds v[c] = score(t, c*64+s));
    // write normalized P into sP[s][t] = sBig[s*8+t]. sBig buf-0 region is
    // last read at chunk-6 reduce; chunk-7 reduce reads buf 1 -> safe.
    if (tid < 512) {
        const int t = w;  // tid>>6
        float m = -1e30f;
        #pragma unroll
        for (int j = 0; j < 8; ++j) m = fmaxf(m, v[j]);
        #pragma unroll
        for (int off = 32; off; off >>= 1) m = fmaxf(m, __shfl_xor(m, off));
        float sum = 0.f;
        #pragma unroll
        for (int j = 0; j < 8; ++j) {
            v[j] = __builtin_amdgcn_exp2f((v[j] - m) * LOG2E);
            sum += v[j];
        }
        #pragma unroll
        for (int off = 32; off; off >>= 1) sum += __shfl_xor(sum, off);
        const float inv = __builtin_amdgcn_rcpf(sum);
        #pragma unroll
        for (int j = 0; j < 8; ++j)
            sBig[(j * 64 + lane) * 8 + t] = v[j] * inv;
    }
    __syncthreads();

    // ---- pax: wave w owns s-strip [32w, 32w+32), all 8 t ----
    float4 acc[8];
    #pragma unroll
    for (int t = 0; t < 8; ++t) acc[t] = make_float4(0.f, 0.f, 0.f, 0.f);

    #pragma unroll 4
    for (int si = 0; si < 32; ++si) {
        const int s = w * 32 + si;
        const float4 xv  = (si < 4) ? xpre[si & 3]
                                    : x4[(b * SEQ + s) * 64 + lane];
        const float4 p03 = *(const float4*)&sBig[s * 8];
        const float4 p47 = *(const float4*)&sBig[s * 8 + 4];
        acc[0].x = fmaf(p03.x, xv.x, acc[0].x); acc[0].y = fmaf(p03.x, xv.y, acc[0].y);
        acc[0].z = fmaf(p03.x, xv.z, acc[0].z); acc[0].w = fmaf(p03.x, xv.w, acc[0].w);
        acc[1].x = fmaf(p03.y, xv.x, acc[1].x); acc[1].y = fmaf(p03.y, xv.y, acc[1].y);
        acc[1].z = fmaf(p03.y, xv.z, acc[1].z); acc[1].w = fmaf(p03.y, xv.w, acc[1].w);
        acc[2].x = fmaf(p03.z, xv.x, acc[2].x); acc[2].y = fmaf(p03.z, xv.y, acc[2].y);
        acc[2].z = fmaf(p03.z, xv.z, acc[2].z); acc[2].w = fmaf(p03.z, xv.w, acc[2].w);
        acc[3].x = fmaf(p03.w, xv.x, acc[3].x); acc[3].y = fmaf(p03.w, xv.y, acc[3].y);
        acc[3].z = fmaf(p03.w, xv.z, acc[3].z); acc[3].w = fmaf(p03.w, xv.w, acc[3].w);
        acc[4].x = fmaf(p47.x, xv.x, acc[4].x); acc[4].y = fmaf(p47.x, xv.y, acc[4].y);
        acc[4].z = fmaf(p47.x, xv.z, acc[4].z); acc[4].w = fmaf(p47.x, xv.w, acc[4].w);
        acc[5].x = fmaf(p47.y, xv.x, acc[5].x); acc[5].y = fmaf(p47.y, xv.y, acc[5].y);
        acc[5].z = fmaf(p47.y, xv.z, acc[5].z); acc[5].w = fmaf(p47.y, xv.w, acc[5].w);
        acc[6].x = fmaf(p47.z, xv.x, acc[6].x); acc[6].y = fmaf(p47.z, xv.y, acc[6].y);
        acc[6].z = fmaf(p47.z, xv.z, acc[6].z); acc[6].w = fmaf(p47.z, xv.w, acc[6].w);
        acc[7].x = fmaf(p47.w, xv.x, acc[7].x); acc[7].y = fmaf(p47.w, xv.y, acc[7].y);
        acc[7].z = fmaf(p47.w, xv.z, acc[7].z); acc[7].w = fmaf(p47.w, xv.w, acc[7].w);
    }
    __syncthreads();   // sP fully consumed; sBig reused as sRed

    float4* sRed4 = (float4*)sBig;     // [8 q][8 t][64 lanes]
    if (w < 8) {
        #pragma unroll
        for (int t = 0; t < 8; ++t)
            sRed4[w * 512 + t * 64 + lane] = acc[t];
    }
    __syncthreads();
    if (w >= 8) {
        #pragma unroll
        for (int t = 0; t < 8; ++t) {
            float4 r = sRed4[(w - 8) * 512 + t * 64 + lane];
            r.x += acc[t].x; r.y += acc[t].y; r.z += acc[t].z; r.w += acc[t].w;
            sRed4[(w - 8) * 512 + t * 64 + lane] = r;
        }
    }
    __syncthreads();
    #pragma unroll
    for (int j = 0; j < 2; ++j) {
        const int i = tid + j * 1024;  // [0,2048): t = i>>8, d = i&255
        const int t = i >> 8, d = i & 255;
        float r = 0.f;
        #pragma unroll
        for (int q = 0; q < 8; ++q) r += sBig[q * 2048 + t * 256 + d];
        out[(b * SEQ + t0 + t) * DDIM + d] = r;
    }
}

extern "C" void kernel_launch(void* const* d_in, const int* in_sizes, int n_in,
                              void* d_out, int out_size, void* d_ws, size_t ws_size,
                              hipStream_t stream) {
    const float* x   = (const float*)d_in[0];   // (4,512,256)
    const float* y   = (const float*)d_in[1];   // (4,512,256)
    const float* W1  = (const float*)d_in[2];   // (128,256)
    const float* W2  = (const float*)d_in[3];   // (128,256)
    const float* vc  = (const float*)d_in[4];   // (1,128)
    float* outp = (float*)d_out;                // (4,512,256)

    float* ws = (float*)d_ws;
    float* e1 = ws;                             // 1 MB (swizzled)
    float* e2 = ws + NB * SEQ * HDIM;           // 1 MB

    hipLaunchKernelGGL(proj_kernel,      dim3(512), dim3(256),  0, stream,
                       x, y, W1, W2, e1, e2);
    hipLaunchKernelGGL(score_pax_kernel, dim3(256), dim3(1024), 0, stream,
                       e1, e2, vc, x, outp);
}

// Round 9
// 93.360 us; speedup vs baseline: 1.0600x; 1.0600x over previous
//
#include <hip/hip_runtime.h>

// B=4, Sx=Sy=512, H=128, D=2H=256, fp32.
// e1 = exp2(2log2e * x@W1^T)  (stored PRE-SWIZZLED: [b][c][hq][s^hq] float4)
// e2 = exp2(2log2e * y@W2^T)  (linear)
// tanh(s1+s2) = 1 - 2/(e1*e2+1); score = sum_h vc[h]*tanh(.)
// constant sum_h vc[h] dropped (softmax shift-invariant); -2 folded into the
// chunk reduce. P = softmax_s(score); out = P @ x.
// Quad-rcp: v1/f1+..+v4/f4 = (n12*f34+n34*f12)/(f12*f34), one rcp per 4 h.
//
// R8:  harness 256 MiB d_ws fill = ~41 us fixed tax (at HBM roofline).
//      Harness reset memsets ~21-22 us fixed (back-computed from R1).
// R11: FAILED: LDS float atomicAdd under 16-way collision.
// R12: e1 direct from global (no intra-block reuse in G=16 layout).
// R13: proj W-load coalescing (wtrans). 99.3us.
// R14: prefetch/occupancy: -1.3us. LESSON: 8 vs 4 waves/SIMD not binding.
// R15: score+pax fused (P stays in LDS): -2.1us (95.9).
// R16: FAILED (container hang x2): cooperative grid.sync not preserved
//      through hipGraph capture/replay. Never retry.
// R17: wtrans deleted via interleaved-k proj footprint (coalesced W loads
//      in original layout); 2 dispatches. 91.95us == measured best.
// R18: FAILED (+7us): full unroll of chunk loop (~2000-inst body, I$
//      thrash) + xpre register pressure. LESSON: R17 codegen was already
//      good; "safe" compiler hints are not safe. THIS IS THE R17 REVERT.

#define NB 4
#define SEQ 512
#define HDIM 128
#define DDIM 256

static constexpr float TWO_LOG2E = 2.8853900817779268f; // 2*log2(e)
static constexpr float LOG2E     = 1.4426950408889634f;

// ---------------- Kernel A: fused projection + exp2 -----------------------
// 512 blocks x 256 thr. Block = 8 rows of x (gr0<2048) or y, full K=256.
// Thread (hq = tid>>3, ks = tid&7); k-footprint interleaved: float4 index
// kf = u*8 + ks. W loads coalesce in the ORIGINAL [h][k] layout.
__global__ __launch_bounds__(256) void proj_kernel(
    const float* __restrict__ x, const float* __restrict__ y,
    const float* __restrict__ W1, const float* __restrict__ W2,
    float* __restrict__ e1sw, float* __restrict__ e2)
{
    __shared__ float As[2048];      // [8 r][256 k]
    __shared__ float sPr[8192];     // [8 ks][8 r][128 h]
    const int tid = threadIdx.x;
    const int gr0 = blockIdx.x * 8;       // global virtual row base [0,4096)

    const float* in; const float* W; int srow;
    if (gr0 < 2048) { in = x; W = W1; srow = gr0; }
    else            { in = y; W = W2; srow = gr0 - 2048; }

    #pragma unroll
    for (int j = 0; j < 2; ++j) {
        const int idx = tid + j * 256;        // float4 slot [0,512)
        const int r = idx >> 6, kk = idx & 63;
        *(float4*)&As[idx * 4] =
            *(const float4*)&in[(srow + r) * 256 + kk * 4];
    }
    __syncthreads();

    const int hq = tid >> 3;   // h-quad [0,32)
    const int ks = tid & 7;    // k-interleave slot [0,8)
    const float4* W4  = (const float4*)W;    // row stride 64 float4
    const float4* As4 = (const float4*)As;   // row stride 64 float4

    float4 acc4[8];
    #pragma unroll
    for (int r = 0; r < 8; ++r) acc4[r] = make_float4(0.f, 0.f, 0.f, 0.f);

    #pragma unroll
    for (int u = 0; u < 8; ++u) {
        const int kf = u * 8 + ks;           // interleaved k-float4 index
        const float4 w0 = W4[(4 * hq + 0) * 64 + kf];
        const float4 w1 = W4[(4 * hq + 1) * 64 + kf];
        const float4 w2 = W4[(4 * hq + 2) * 64 + kf];
        const float4 w3 = W4[(4 * hq + 3) * 64 + kf];
        #pragma unroll
        for (int r = 0; r < 8; ++r) {
            const float4 a = As4[r * 64 + kf];
            acc4[r].x = fmaf(a.w,w0.w, fmaf(a.z,w0.z, fmaf(a.y,w0.y, fmaf(a.x,w0.x, acc4[r].x))));
            acc4[r].y = fmaf(a.w,w1.w, fmaf(a.z,w1.z, fmaf(a.y,w1.y, fmaf(a.x,w1.x, acc4[r].y))));
            acc4[r].z = fmaf(a.w,w2.w, fmaf(a.z,w2.z, fmaf(a.y,w2.y, fmaf(a.x,w2.x, acc4[r].z))));
            acc4[r].w = fmaf(a.w,w3.w, fmaf(a.z,w3.z, fmaf(a.y,w3.y, fmaf(a.x,w3.x, acc4[r].w))));
        }
    }
    #pragma unroll
    for (int r = 0; r < 8; ++r)
        *(float4*)&sPr[ks * 1024 + r * 128 + hq * 4] = acc4[r];
    __syncthreads();
    {
        const int r = tid >> 5, h4 = tid & 31;
        float4 s = make_float4(0.f, 0.f, 0.f, 0.f);
        #pragma unroll
        for (int k2 = 0; k2 < 8; ++k2) {
            const float4 p = *(const float4*)&sPr[k2 * 1024 + r * 128 + h4 * 4];
            s.x += p.x; s.y += p.y; s.z += p.z; s.w += p.w;
        }
        float4 o;
        o.x = __builtin_amdgcn_exp2f(s.x * TWO_LOG2E);
        o.y = __builtin_amdgcn_exp2f(s.y * TWO_LOG2E);
        o.z = __builtin_amdgcn_exp2f(s.z * TWO_LOG2E);
        o.w = __builtin_amdgcn_exp2f(s.w * TWO_LOG2E);
        const int gr = gr0 + r;
        if (gr < 2048) {
            const int b = gr >> 9, ss = gr & 511;
            const int c = ss >> 6, sl = ss & 63;
            ((float4*)e1sw)[((b * 8 + c) * 32 + h4) * 64 + (sl ^ h4)] = o;
        } else {
            ((float4*)e2)[(gr - 2048) * 32 + h4] = o;
        }
    }
}

// ---------------- Kernel B: fused scores + softmax + P@x -------------------
// 256 blocks x 1024 thr (16 waves). Block = (b, 8 t-rows). Phase 1: wave w
// = h-group hg computes partial scores for ALL 8 t per e1 value (e1 direct
// from global, depth-1 prefetch). Per chunk: partials -> sPartC[c&1],
// barrier, tid<512 accumulate the 16-wave sum into registers v[c]. Then
// softmax on v[], normalized P into LDS sP[s][t]. Phase 2: pax; P never
// touches global. LDS: 64 KB arena.
__global__ __launch_bounds__(1024) void score_pax_kernel(
    const float* __restrict__ e1sw, const float* __restrict__ e2g,
    const float* __restrict__ vc,  const float* __restrict__ x,
    float* __restrict__ out)
{
    __shared__ float sBig[16384];   // 64 KB arena

    const int tid  = threadIdx.x;
    const int b    = blockIdx.x >> 6;
    const int t0   = (blockIdx.x & 63) * 8;
    const int w    = tid >> 6;
    const int lane = tid & 63;
    const int wu   = __builtin_amdgcn_readfirstlane(w);
    const int hg   = wu;               // h-group: quads 2hg, 2hg+1

    // scalar operands: 2 vc quads + 8t x 2 e2 quads (wave-uniform addrs)
    float4 vcs[2];
    float4 e2s[8][2];
    #pragma unroll
    for (int j = 0; j < 2; ++j)
        vcs[j] = *(const float4*)&vc[(hg * 2 + j) * 4];
    #pragma unroll
    for (int t = 0; t < 8; ++t)
        #pragma unroll
        for (int j = 0; j < 2; ++j)
            e2s[t][j] = *(const float4*)&e2g[(b * SEQ + t0 + t) * HDIM + (hg * 2 + j) * 4];

    const float4* e1c = (const float4*)e1sw + b * 16384;  // 8 chunks x 2048

    // fixed per-lane offsets of the two h-quad loads within a chunk
    const int off0 = (hg * 2 + 0) * 64 + (lane ^ (hg * 2 + 0));
    const int off1 = (hg * 2 + 1) * 64 + (lane ^ (hg * 2 + 1));

    float4 e1v0 = e1c[off0];
    float4 e1v1 = e1c[off1];

    float v[8];   // v[c] = score(t = tid>>6, s = c*64 + lane) for tid<512

    for (int c = 0; c < 8; ++c) {
        float4 e1n0 = e1v0, e1n1 = e1v1;
        if (c < 7) {
            const float4* nx = e1c + (c + 1) * 2048;
            e1n0 = nx[off0];
            e1n1 = nx[off1];
        }
        float acc[8];
        #pragma unroll
        for (int t = 0; t < 8; ++t) acc[t] = 0.f;
        #pragma unroll
        for (int j = 0; j < 2; ++j) {
            const float4 e1 = j ? e1v1 : e1v0;
            const float4 vv = vcs[j];
            #pragma unroll
            for (int t = 0; t < 8; ++t) {
                const float4 e2 = e2s[t][j];
                const float f1 = fmaf(e1.x, e2.x, 1.f);
                const float f2 = fmaf(e1.y, e2.y, 1.f);
                const float f3 = fmaf(e1.z, e2.z, 1.f);
                const float f4 = fmaf(e1.w, e2.w, 1.f);
                const float f12 = f1 * f2, f34 = f3 * f4;
                const float n12 = fmaf(vv.x, f2, vv.y * f1);
                const float n34 = fmaf(vv.z, f4, vv.w * f3);
                const float num = fmaf(n12, f34, n34 * f12);
                acc[t] = fmaf(num, __builtin_amdgcn_rcpf(f12 * f34), acc[t]);
            }
        }
        // partials: sPartC[c&1][w][t][64 s]
        float* pb = sBig + (c & 1) * 8192 + wu * 512 + lane;
        #pragma unroll
        for (int t = 0; t < 8; ++t) pb[t * 64] = acc[t];
        __syncthreads();
        if (tid < 512) {
            const int t = tid >> 6, s = tid & 63;
            const float* pc = sBig + (c & 1) * 8192 + t * 64 + s;
            float r = 0.f;
            #pragma unroll
            for (int ww = 0; ww < 16; ++ww) r += pc[ww * 512];
            v[c] = -2.f * r;
        }
        e1v0 = e1n0;
        e1v1 = e1n1;
    }

    // softmax by tid<512 (thread (t,s) holds v[c] = score(t, c*64+s));
    // write normalized P into sP[s][t] = sBig[s*8+t]. sBig buf-0 region is
    // last read at chunk-6 reduce; chunk-7 reduce reads buf 1 -> safe.
    if (tid < 512) {
        const int t = w;  // tid>>6
        float m = -1e30f;
        #pragma unroll
        for (int j = 0; j < 8; ++j) m = fmaxf(m, v[j]);
        #pragma unroll
        for (int off = 32; off; off >>= 1) m = fmaxf(m, __shfl_xor(m, off));
        float sum = 0.f;
        #pragma unroll
        for (int j = 0; j < 8; ++j) {
            v[j] = __builtin_amdgcn_exp2f((v[j] - m) * LOG2E);
            sum += v[j];
        }
        #pragma unroll
        for (int off = 32; off; off >>= 1) sum += __shfl_xor(sum, off);
        const float inv = __builtin_amdgcn_rcpf(sum);
        #pragma unroll
        for (int j = 0; j < 8; ++j)
            sBig[(j * 64 + lane) * 8 + t] = v[j] * inv;
    }
    __syncthreads();

    // ---- pax: wave w owns s-strip [32w, 32w+32), all 8 t ----
    const float4* x4 = (const float4*)x;
    float4 acc[8];
    #pragma unroll
    for (int t = 0; t < 8; ++t) acc[t] = make_float4(0.f, 0.f, 0.f, 0.f);

    #pragma unroll 4
    for (int si = 0; si < 32; ++si) {
        const int s = w * 32 + si;
        const float4 xv  = x4[(b * SEQ + s) * 64 + lane];
        const float4 p03 = *(const float4*)&sBig[s * 8];
        const float4 p47 = *(const float4*)&sBig[s * 8 + 4];
        acc[0].x = fmaf(p03.x, xv.x, acc[0].x); acc[0].y = fmaf(p03.x, xv.y, acc[0].y);
        acc[0].z = fmaf(p03.x, xv.z, acc[0].z); acc[0].w = fmaf(p03.x, xv.w, acc[0].w);
        acc[1].x = fmaf(p03.y, xv.x, acc[1].x); acc[1].y = fmaf(p03.y, xv.y, acc[1].y);
        acc[1].z = fmaf(p03.y, xv.z, acc[1].z); acc[1].w = fmaf(p03.y, xv.w, acc[1].w);
        acc[2].x = fmaf(p03.z, xv.x, acc[2].x); acc[2].y = fmaf(p03.z, xv.y, acc[2].y);
        acc[2].z = fmaf(p03.z, xv.z, acc[2].z); acc[2].w = fmaf(p03.z, xv.w, acc[2].w);
        acc[3].x = fmaf(p03.w, xv.x, acc[3].x); acc[3].y = fmaf(p03.w, xv.y, acc[3].y);
        acc[3].z = fmaf(p03.w, xv.z, acc[3].z); acc[3].w = fmaf(p03.w, xv.w, acc[3].w);
        acc[4].x = fmaf(p47.x, xv.x, acc[4].x); acc[4].y = fmaf(p47.x, xv.y, acc[4].y);
        acc[4].z = fmaf(p47.x, xv.z, acc[4].z); acc[4].w = fmaf(p47.x, xv.w, acc[4].w);
        acc[5].x = fmaf(p47.y, xv.x, acc[5].x); acc[5].y = fmaf(p47.y, xv.y, acc[5].y);
        acc[5].z = fmaf(p47.y, xv.z, acc[5].z); acc[5].w = fmaf(p47.y, xv.w, acc[5].w);
        acc[6].x = fmaf(p47.z, xv.x, acc[6].x); acc[6].y = fmaf(p47.z, xv.y, acc[6].y);
        acc[6].z = fmaf(p47.z, xv.z, acc[6].z); acc[6].w = fmaf(p47.z, xv.w, acc[6].w);
        acc[7].x = fmaf(p47.w, xv.x, acc[7].x); acc[7].y = fmaf(p47.w, xv.y, acc[7].y);
        acc[7].z = fmaf(p47.w, xv.z, acc[7].z); acc[7].w = fmaf(p47.w, xv.w, acc[7].w);
    }
    __syncthreads();   // sP fully consumed; sBig reused as sRed

    float4* sRed4 = (float4*)sBig;     // [8 q][8 t][64 lanes]
    if (w < 8) {
        #pragma unroll
        for (int t = 0; t < 8; ++t)
            sRed4[w * 512 + t * 64 + lane] = acc[t];
    }
    __syncthreads();
    if (w >= 8) {
        #pragma unroll
        for (int t = 0; t < 8; ++t) {
            float4 r = sRed4[(w - 8) * 512 + t * 64 + lane];
            r.x += acc[t].x; r.y += acc[t].y; r.z += acc[t].z; r.w += acc[t].w;
            sRed4[(w - 8) * 512 + t * 64 + lane] = r;
        }
    }
    __syncthreads();
    #pragma unroll
    for (int j = 0; j < 2; ++j) {
        const int i = tid + j * 1024;  // [0,2048): t = i>>8, d = i&255
        const int t = i >> 8, d = i & 255;
        float r = 0.f;
        #pragma unroll
        for (int q = 0; q < 8; ++q) r += sBig[q * 2048 + t * 256 + d];
        out[(b * SEQ + t0 + t) * DDIM + d] = r;
    }
}

extern "C" void kernel_launch(void* const* d_in, const int* in_sizes, int n_in,
                              void* d_out, int out_size, void* d_ws, size_t ws_size,
                              hipStream_t stream) {
    const float* x   = (const float*)d_in[0];   // (4,512,256)
    const float* y   = (const float*)d_in[1];   // (4,512,256)
    const float* W1  = (const float*)d_in[2];   // (128,256)
    const float* W2  = (const float*)d_in[3];   // (128,256)
    const float* vc  = (const float*)d_in[4];   // (1,128)
    float* outp = (float*)d_out;                // (4,512,256)

    float* ws = (float*)d_ws;
    float* e1 = ws;                             // 1 MB (swizzled)
    float* e2 = ws + NB * SEQ * HDIM;           // 1 MB

    hipLaunchKernelGGL(proj_kernel,      dim3(512), dim3(256),  0, stream,
                       x, y, W1, W2, e1, e2);
    hipLaunchKernelGGL(score_pax_kernel, dim3(256), dim3(1024), 0, stream,
                       e1, e2, vc, x, outp);
}